// Round 13
// baseline (349.428 us; speedup 1.0000x reference)
//
#include <hip/hip_runtime.h>
#include <hip/hip_bf16.h>

typedef __attribute__((ext_vector_type(4))) float f32x4;
typedef __attribute__((ext_vector_type(8))) __bf16 bf16x8;
typedef __attribute__((ext_vector_type(8))) short short8;
typedef __attribute__((ext_vector_type(4))) short short4v;
typedef __attribute__((ext_vector_type(2))) unsigned int uint2v;
typedef __attribute__((ext_vector_type(4))) unsigned int uint4v;

#define SEQ 4096
#define NQKV 3072

static __device__ __forceinline__ unsigned short f2bf(float x) {
  unsigned int u = __float_as_uint(x);
  u += 0x7fffu + ((u >> 16) & 1u);   // RTNE
  return (unsigned short)(u >> 16);
}
static __device__ __forceinline__ float bf2f(unsigned short b) {
  return __uint_as_float(((unsigned int)b) << 16);
}
static __device__ __forceinline__ unsigned int cvtpk_bf16(float lo, float hi) {
  unsigned int r;
  asm("v_cvt_pk_bf16_f32 %0, %1, %2" : "=v"(r) : "v"(lo), "v"(hi));
  return r;
}
static __device__ __forceinline__ float exp2_fast(float x) {
  float r;
  asm("v_exp_f32 %0, %1" : "=v"(r) : "v"(x));
  return r;
}

// ---------------- fused fp32 -> bf16 convert (single launch) ----------------
__global__ void cvt_all(const float* __restrict__ hs, const float* __restrict__ wq,
                        const float* __restrict__ wk, const float* __restrict__ wv,
                        const float* __restrict__ wo,
                        unsigned short* __restrict__ Xb, unsigned short* __restrict__ Wqkv,
                        unsigned short* __restrict__ Wob) {
  int i = blockIdx.x * blockDim.x + threadIdx.x;   // 8388608 total
  const float* src;
  unsigned short* dst;
  int off;
  if (i < 4194304)      { src = hs; dst = Xb;              off = i; }
  else if (i < 6291456) { src = wq; dst = Wqkv;            off = i - 4194304; }
  else if (i < 6815744) { src = wk; dst = Wqkv + 8388608;  off = i - 6291456; }
  else if (i < 7340032) { src = wv; dst = Wqkv + 10485760; off = i - 6815744; }
  else                  { src = wo; dst = Wob;             off = i - 7340032; }
  f32x4 v = ((const f32x4*)src)[off];
  short4v o;
#pragma unroll
  for (int j = 0; j < 4; ++j) o[j] = (short)f2bf(v[j]);
  ((short4v*)dst)[off] = o;
}

// ---------------- deep-pipelined bf16 GEMM: C = A(MxK) @ Bt(NxK)^T ----------
// 256 x BN tile, BK=32, 8 waves (2Mx4N), 3-buffer LDS ring, prefetch dist 2,
// counted vmcnt once per K-step (never 0 in steady state).
// NEW (m201-style T3): each K-step split into 2 phases (M-halves); per phase
// {ds_read subtile + issue half the stage loads -> barrier -> lgkmcnt(0) ->
//  setprio(1) MFMA setprio(0) -> barrier}.
template <int BN, bool OUT_F32>
__global__ __launch_bounds__(512, 1) void gemm256(const unsigned short* __restrict__ A,
                                                  const unsigned short* __restrict__ Bt,
                                                  void* __restrict__ Cp,
                                                  int M, int N, int K) {
  constexpr int NJ = BN / 64;
  constexpr int TC = 16 + BN / 16;
  constexpr int SPW = (TC + 7) / 8;
  constexpr int DUP = 8 * SPW - TC;
  constexpr int SHALF = SPW / 2;          // stage instrs in phase A

  __shared__ unsigned short AbL[3][8192];
  __shared__ unsigned short BbL[3][BN * 32];

  const int t512 = threadIdx.x;
  const int l = t512 & 63;
  const int wid = t512 >> 6;
  const int wm = wid >> 2, wn = wid & 3;
  const int lr = l & 15, lg = l >> 4;

  const int bid = blockIdx.y * 16 + blockIdx.x;
  const int nid = (bid & 7) * 32 + (bid >> 3);
  const int m0 = (nid >> 4) * 256, n0 = (nid & 15) * BN;

  const int lrow = l >> 2;
  const int scb = ((l & 3) << 4) ^ ((lrow & 3) << 4);
  const int rswz = (lr & 3) << 4;

  f32x4 acc[8][NJ];
#pragma unroll
  for (int i = 0; i < 8; ++i)
#pragma unroll
    for (int j = 0; j < NJ; ++j) acc[i][j] = (f32x4){0.f, 0.f, 0.f, 0.f};

  auto stage_part = [&](int buf, int t, int s0, int s1) {
#pragma unroll
    for (int s = s0; s < s1; ++s) {
      const int kt = t * 32;
      int id = wid * SPW + s;
      if (DUP > 0 && id >= TC) id -= DUP;
      if (id < 16) {
        const char* src = (const char*)(A + (size_t)(m0 + id * 16 + lrow) * K + kt) + scb;
        __builtin_amdgcn_global_load_lds(
            (const __attribute__((address_space(1))) void*)src,
            (__attribute__((address_space(3))) void*)&AbL[buf][id * 512], 16, 0, 0);
      } else {
        const int b = id - 16;
        const char* src = (const char*)(Bt + (size_t)(n0 + b * 16 + lrow) * K + kt) + scb;
        __builtin_amdgcn_global_load_lds(
            (const __attribute__((address_space(1))) void*)src,
            (__attribute__((address_space(3))) void*)&BbL[buf][b * 512], 16, 0, 0);
      }
    }
  };

  const int NT = K / 32;

  stage_part(0, 0, 0, SPW);
  stage_part(1, 1, 0, SPW);
  if constexpr (SPW == 4) asm volatile("s_waitcnt vmcnt(4)" ::: "memory");
  else                    asm volatile("s_waitcnt vmcnt(3)" ::: "memory");
  __builtin_amdgcn_s_barrier();
  asm volatile("" ::: "memory");

  int cur = 0;
  for (int t = 0; t < NT; ++t) {
    int pf = cur + 2; if (pf >= 3) pf -= 3;
    const bool do_stage = (t + 2 < NT);

    const char* Ab0 = (const char*)&AbL[cur][0] + (size_t)(wm * 128 + lr) * 64;
    const char* Bb0 = (const char*)&BbL[cur][0] + (size_t)(wn * (BN / 4) + lr) * 64;

    // ---------------- phase A: B-frags + A-half0, first stage half ----------
    bf16x8 bfv[NJ], afA[4];
#pragma unroll
    for (int j = 0; j < NJ; ++j)
      bfv[j] = *(const bf16x8*)(Bb0 + j * 1024 + ((lg * 16) ^ rswz));
#pragma unroll
    for (int i = 0; i < 4; ++i)
      afA[i] = *(const bf16x8*)(Ab0 + i * 1024 + ((lg * 16) ^ rswz));
    if (do_stage) stage_part(pf, t + 2, 0, SHALF);
    __builtin_amdgcn_s_barrier();
    asm volatile("s_waitcnt lgkmcnt(0)" ::: "memory");
    __builtin_amdgcn_sched_barrier(0);
    __builtin_amdgcn_s_setprio(1);
#pragma unroll
    for (int i = 0; i < 4; ++i)
#pragma unroll
      for (int j = 0; j < NJ; ++j)
        acc[i][j] = __builtin_amdgcn_mfma_f32_16x16x32_bf16(afA[i], bfv[j], acc[i][j], 0, 0, 0);
    __builtin_amdgcn_s_setprio(0);
    __builtin_amdgcn_s_barrier();

    // ---------------- phase B: A-half1, second stage half -------------------
    bf16x8 afB[4];
#pragma unroll
    for (int i = 0; i < 4; ++i)
      afB[i] = *(const bf16x8*)(Ab0 + (4 + i) * 1024 + ((lg * 16) ^ rswz));
    if (do_stage) stage_part(pf, t + 2, SHALF, SPW);
    __builtin_amdgcn_s_barrier();
    asm volatile("s_waitcnt lgkmcnt(0)" ::: "memory");
    __builtin_amdgcn_sched_barrier(0);
    __builtin_amdgcn_s_setprio(1);
#pragma unroll
    for (int i = 0; i < 4; ++i)
#pragma unroll
      for (int j = 0; j < NJ; ++j)
        acc[4 + i][j] = __builtin_amdgcn_mfma_f32_16x16x32_bf16(afB[i], bfv[j], acc[4 + i][j], 0, 0, 0);
    __builtin_amdgcn_s_setprio(0);

    if (do_stage) {
      if constexpr (SPW == 4) asm volatile("s_waitcnt vmcnt(4)" ::: "memory");
      else                    asm volatile("s_waitcnt vmcnt(3)" ::: "memory");
    } else if (t + 1 < NT) {
      asm volatile("s_waitcnt vmcnt(0)" ::: "memory");
    }
    if (t + 1 < NT) {
      __builtin_amdgcn_s_barrier();
      asm volatile("" ::: "memory");
    }
    cur = (cur == 2) ? 0 : cur + 1;
  }

  const int row0 = m0 + wm * 128, col0 = n0 + wn * (BN / 4);
#pragma unroll
  for (int i = 0; i < 8; ++i) {
#pragma unroll
    for (int j = 0; j < NJ; ++j) {
      const int col = col0 + j * 16 + lr;
#pragma unroll
      for (int r = 0; r < 4; ++r) {
        const int row = row0 + i * 16 + lg * 4 + r;
        if (OUT_F32)
          ((float*)Cp)[(size_t)row * N + col] = acc[i][j][r];
        else
          ((unsigned short*)Cp)[(size_t)row * N + col] = f2bf(acc[i][j][r]);
      }
    }
  }
}

// ---------------- RoPE (+ fold 0.125*log2e into Q) ----------------
__global__ void rope_scale(unsigned short* __restrict__ qkv,
                           const float* __restrict__ fc,
                           const float* __restrict__ fs) {
  int idx = blockIdx.x * blockDim.x + threadIdx.x;
  int s = idx / 1280;
  int p = idx - s * 1280;
  bool isQ = (p < 1024);
  int col = isQ ? (p * 2) : (2048 + (p - 1024) * 2);
  int fi = (col >> 1) & 31;
  float c = fc[s * 32 + fi];
  float sn = fs[s * 32 + fi];
  unsigned short* ptr = qkv + (size_t)s * NQKV + col;
  float x0 = bf2f(ptr[0]);
  float x1 = bf2f(ptr[1]);
  float o0 = x0 * c - x1 * sn;
  float o1 = x0 * sn + x1 * c;
  float scl = isQ ? 0.1803368801111204f : 1.0f;  // 0.125 * log2(e) on Q only
  ptr[0] = f2bf(o0 * scl);
  ptr[1] = f2bf(o1 * scl);
}

// ---------------- V transpose + kappa key-permute (as round 12) -------------
__global__ void v_transpose(const unsigned short* __restrict__ qkv,
                            unsigned short* __restrict__ Vt) {
  __shared__ unsigned short tile[64][72];
  const int kvh = blockIdx.x;
  const int st = blockIdx.y * 64;
  const int t = threadIdx.x;
  const int sl = t >> 2, d0 = (t & 3) * 16;
  const unsigned short* src = qkv + (size_t)(st + sl) * NQKV + 2560 + kvh * 64 + d0;
  *(bf16x8*)&tile[sl][d0] = *(const bf16x8*)src;
  *(bf16x8*)&tile[sl][d0 + 8] = *(const bf16x8*)(src + 8);
  __syncthreads();
  const int dl = t >> 2, s0 = (t & 3) * 16;
  unsigned short* dst = Vt + ((size_t)kvh * 64 + dl) * 4096 + st + s0;
#pragma unroll
  for (int j2 = 0; j2 < 2; ++j2) {
    short8 v;
#pragma unroll
    for (int j = 0; j < 8; ++j) {
      const int pos = s0 + j2 * 8 + j;
      const int key = (pos & 32) + ((pos & 4) << 2) + (((pos >> 3) & 3) << 2) + (pos & 3);
      v[j] = (short)tile[key][dl];
    }
    *(short8*)(dst + j2 * 8) = v;
  }
}

// ---------------- flash attention (round-12 verified, unchanged) ------------
__global__ __launch_bounds__(256, 4) void attn_fwd(const unsigned short* __restrict__ qkv,
                                                   const unsigned short* __restrict__ Vt,
                                                   unsigned short* __restrict__ attn) {
  __shared__ unsigned short Ks[2][4096];
  __shared__ unsigned short Vs[2][4096];

  const int t = threadIdx.x;
  const int l = t & 63;
  const int w = t >> 6;
  const int lr = l & 15, lg = l >> 4;
  const int h = blockIdx.x;
  const int kvh = h >> 2;
  const int qbase = blockIdx.y * 128 + w * 32;

  const int chunk0 = w * 2;
  const int srow = l >> 3;
  const int scol = (l & 7) * 16;
  const int sorig = scol ^ ((srow & 7) << 4);
  const char* ksrc0 = (const char*)(qkv + 2048 + kvh * 64) +
                      (size_t)(chunk0 * 8 + srow) * (NQKV * 2) + sorig;
  const char* ksrc1 = ksrc0 + 8 * (NQKV * 2);
  const char* vsrc0 = (const char*)(Vt + (size_t)kvh * 64 * 4096) +
                      (size_t)(chunk0 * 8 + srow) * 8192 + sorig;
  const char* vsrc1 = vsrc0 + 8 * 8192;

  const int x = (lr & 7) << 4;
  const int x6 = x & 64, x45 = x & 48;
  const int offA = lr * 128 + x6 + ((lg * 16) ^ x45);
  const int offB = lr * 128 + (64 ^ x6) + ((lg * 16) ^ x45);

  bf16x8 qf[2][2];
#pragma unroll
  for (int qi = 0; qi < 2; ++qi) {
    const unsigned short* qr = qkv + (size_t)(qbase + qi * 16 + lr) * NQKV + h * 64;
    qf[qi][0] = *(const bf16x8*)(qr + lg * 8);
    qf[qi][1] = *(const bf16x8*)(qr + 32 + lg * 8);
  }

  f32x4 ls4[2];
  f32x4 o[2][4];
#pragma unroll
  for (int qi = 0; qi < 2; ++qi) {
    ls4[qi] = (f32x4){0.f, 0.f, 0.f, 0.f};
#pragma unroll
    for (int c4 = 0; c4 < 4; ++c4) o[qi][c4] = (f32x4){0.f, 0.f, 0.f, 0.f};
  }

  auto stage = [&](int buf, int tile) {
    const size_t kadv = (size_t)tile * 64 * (NQKV * 2);
    const size_t vadv = (size_t)tile * 128;
    __builtin_amdgcn_global_load_lds(
        (const __attribute__((address_space(1))) void*)(ksrc0 + kadv),
        (__attribute__((address_space(3))) void*)&Ks[buf][chunk0 * 512], 16, 0, 0);
    __builtin_amdgcn_global_load_lds(
        (const __attribute__((address_space(1))) void*)(ksrc1 + kadv),
        (__attribute__((address_space(3))) void*)&Ks[buf][(chunk0 + 1) * 512], 16, 0, 0);
    __builtin_amdgcn_global_load_lds(
        (const __attribute__((address_space(1))) void*)(vsrc0 + vadv),
        (__attribute__((address_space(3))) void*)&Vs[buf][chunk0 * 512], 16, 0, 0);
    __builtin_amdgcn_global_load_lds(
        (const __attribute__((address_space(1))) void*)(vsrc1 + vadv),
        (__attribute__((address_space(3))) void*)&Vs[buf][(chunk0 + 1) * 512], 16, 0, 0);
  };

  stage(0, 0);
  asm volatile("s_waitcnt vmcnt(0)" ::: "memory");
  __syncthreads();

  const int NT = SEQ / 64;
  for (int tt = 0; tt < NT; ++tt) {
    const int buf = tt & 1;
    if (tt + 1 < NT) stage(buf ^ 1, tt + 1);

    const char* Ksb = (const char*)Ks[buf];
    const char* Vsb = (const char*)Vs[buf];

    f32x4 sc[2][4];
    __builtin_amdgcn_s_setprio(1);
#pragma unroll
    for (int sI = 0; sI < 4; ++sI) {
      bf16x8 kf0 = *(const bf16x8*)(Ksb + offA + sI * 2048);
      bf16x8 kf1 = *(const bf16x8*)(Ksb + offB + sI * 2048);
#pragma unroll
      for (int qi = 0; qi < 2; ++qi) {
        f32x4 c = (f32x4){0.f, 0.f, 0.f, 0.f};
        c = __builtin_amdgcn_mfma_f32_16x16x32_bf16(kf0, qf[qi][0], c, 0, 0, 0);
        c = __builtin_amdgcn_mfma_f32_16x16x32_bf16(kf1, qf[qi][1], c, 0, 0, 0);
        sc[qi][sI] = c;
      }
    }
    __builtin_amdgcn_s_setprio(0);

    bf16x8 pa[2][2];
#pragma unroll
    for (int qi = 0; qi < 2; ++qi) {
      float p[4][4];
#pragma unroll
      for (int sI = 0; sI < 4; ++sI)
#pragma unroll
        for (int r = 0; r < 4; ++r) p[sI][r] = exp2_fast(sc[qi][sI][r]);
#pragma unroll
      for (int sI = 0; sI < 4; ++sI)
#pragma unroll
        for (int r = 0; r < 4; ++r) ls4[qi][r] += p[sI][r];
      uint4v u1, u2;
      u1[0] = cvtpk_bf16(p[0][0], p[0][1]); u1[1] = cvtpk_bf16(p[0][2], p[0][3]);
      u1[2] = cvtpk_bf16(p[1][0], p[1][1]); u1[3] = cvtpk_bf16(p[1][2], p[1][3]);
      u2[0] = cvtpk_bf16(p[2][0], p[2][1]); u2[1] = cvtpk_bf16(p[2][2], p[2][3]);
      u2[2] = cvtpk_bf16(p[3][0], p[3][1]); u2[3] = cvtpk_bf16(p[3][2], p[3][3]);
      pa[qi][0] = __builtin_bit_cast(bf16x8, u1);
      pa[qi][1] = __builtin_bit_cast(bf16x8, u2);
    }

    __builtin_amdgcn_s_setprio(1);
#pragma unroll
    for (int c4 = 0; c4 < 4; ++c4) {
      bf16x8 v0 = *(const bf16x8*)(Vsb + offA + c4 * 2048);
      bf16x8 v1 = *(const bf16x8*)(Vsb + offB + c4 * 2048);
#pragma unroll
      for (int qi = 0; qi < 2; ++qi) {
        o[qi][c4] = __builtin_amdgcn_mfma_f32_16x16x32_bf16(pa[qi][0], v0, o[qi][c4], 0, 0, 0);
        o[qi][c4] = __builtin_amdgcn_mfma_f32_16x16x32_bf16(pa[qi][1], v1, o[qi][c4], 0, 0, 0);
      }
    }
    __builtin_amdgcn_s_setprio(0);

    if (tt + 1 < NT) {
      asm volatile("s_waitcnt vmcnt(0)" ::: "memory");
      __syncthreads();
    }
  }

#pragma unroll
  for (int qi = 0; qi < 2; ++qi) {
    float lsum = ls4[qi][0] + ls4[qi][1] + ls4[qi][2] + ls4[qi][3];
    lsum += __shfl_xor(lsum, 16, 64);
    lsum += __shfl_xor(lsum, 32, 64);
    float inv = 1.f / lsum;
    float invO[4];
#pragma unroll
    for (int r = 0; r < 4; ++r) invO[r] = __shfl(inv, 4 * lg + r, 64);
#pragma unroll
    for (int c4 = 0; c4 < 4; ++c4)
#pragma unroll
      for (int r = 0; r < 4; ++r) {
        attn[(size_t)(qbase + qi * 16 + 4 * lg + r) * 2048 + h * 64 + c4 * 16 + lr] =
            f2bf(o[qi][c4][r] * invO[r]);
      }
  }
}

// ---------------- launch ----------------
extern "C" void kernel_launch(void* const* d_in, const int* in_sizes, int n_in,
                              void* d_out, int out_size, void* d_ws, size_t ws_size,
                              hipStream_t stream) {
  const float* hs = (const float*)d_in[0];
  const float* wq = (const float*)d_in[1];
  const float* wk = (const float*)d_in[2];
  const float* wv = (const float*)d_in[3];
  const float* wo = (const float*)d_in[4];
  const float* fc = (const float*)d_in[5];
  const float* fs = (const float*)d_in[6];
  float* out = (float*)d_out;

  char* ws = (char*)d_ws;
  unsigned short* Xb    = (unsigned short*)(ws);                      // 0..32MB (X bf16)
  unsigned short* Wqkv  = (unsigned short*)(ws + (size_t)(32 << 20)); // 32..56MB
  unsigned short* Wob   = (unsigned short*)(ws + (size_t)(56 << 20)); // 56..64MB
  unsigned short* QKV   = (unsigned short*)(ws + (size_t)(64 << 20)); // 64..88MB
  unsigned short* attnb = Xb;                                         // 0..16MB (X dead)
  unsigned short* Vtb   = (unsigned short*)(ws + (size_t)(16 << 20)); // 16..20MB (X dead)

  cvt_all<<<32768, 256, 0, stream>>>(hs, wq, wk, wv, wo, Xb, Wqkv, Wob);

  // QKV = Xb @ Wqkv^T : M=4096, N=3072, K=4096 (bf16 out), 256x192 tiles
  gemm256<192, false><<<dim3(16, 16), 512, 0, stream>>>(Xb, Wqkv, QKV, 4096, 3072, 4096);

  v_transpose<<<dim3(8, 64), 256, 0, stream>>>(QKV, Vtb);
  rope_scale<<<20480, 256, 0, stream>>>(QKV, fc, fs);

  attn_fwd<<<dim3(32, 32), 256, 0, stream>>>(QKV, Vtb, attnb);

  // out = attn @ Wo^T : M=4096, N=2048, K=2048 (fp32 out), 256x128 tiles
  gemm256<128, true><<<dim3(16, 16), 512, 0, stream>>>(attnb, Wob, out, 4096, 2048, 2048);
}

// Round 14
// 340.143 us; speedup vs baseline: 1.0273x; 1.0273x over previous
//
#include <hip/hip_runtime.h>
#include <hip/hip_bf16.h>

typedef __attribute__((ext_vector_type(4))) float f32x4;
typedef __attribute__((ext_vector_type(8))) __bf16 bf16x8;
typedef __attribute__((ext_vector_type(8))) short short8;
typedef __attribute__((ext_vector_type(4))) short short4v;
typedef __attribute__((ext_vector_type(2))) unsigned int uint2v;
typedef __attribute__((ext_vector_type(4))) unsigned int uint4v;

#define SEQ 4096
#define NQKV 3072

static __device__ __forceinline__ unsigned short f2bf(float x) {
  unsigned int u = __float_as_uint(x);
  u += 0x7fffu + ((u >> 16) & 1u);   // RTNE
  return (unsigned short)(u >> 16);
}
static __device__ __forceinline__ float bf2f(unsigned short b) {
  return __uint_as_float(((unsigned int)b) << 16);
}
static __device__ __forceinline__ unsigned int cvtpk_bf16(float lo, float hi) {
  unsigned int r;
  asm("v_cvt_pk_bf16_f32 %0, %1, %2" : "=v"(r) : "v"(lo), "v"(hi));
  return r;
}
static __device__ __forceinline__ float exp2_fast(float x) {
  float r;
  asm("v_exp_f32 %0, %1" : "=v"(r) : "v"(x));
  return r;
}

// ---------------- fused fp32 -> bf16 convert (single launch) ----------------
__global__ void cvt_all(const float* __restrict__ hs, const float* __restrict__ wq,
                        const float* __restrict__ wk, const float* __restrict__ wv,
                        const float* __restrict__ wo,
                        unsigned short* __restrict__ Xb, unsigned short* __restrict__ Wqkv,
                        unsigned short* __restrict__ Wob) {
  int i = blockIdx.x * blockDim.x + threadIdx.x;   // 8388608 total
  const float* src;
  unsigned short* dst;
  int off;
  if (i < 4194304)      { src = hs; dst = Xb;              off = i; }
  else if (i < 6291456) { src = wq; dst = Wqkv;            off = i - 4194304; }
  else if (i < 6815744) { src = wk; dst = Wqkv + 8388608;  off = i - 6291456; }
  else if (i < 7340032) { src = wv; dst = Wqkv + 10485760; off = i - 6815744; }
  else                  { src = wo; dst = Wob;             off = i - 7340032; }
  f32x4 v = ((const f32x4*)src)[off];
  short4v o;
#pragma unroll
  for (int j = 0; j < 4; ++j) o[j] = (short)f2bf(v[j]);
  ((short4v*)dst)[off] = o;
}

// ---------------- deep-pipelined bf16 GEMM: C = A(MxK) @ Bt(NxK)^T ----------
// (round-12 verified structure: free-scheduled MFMA/ds_read interleave,
//  3-buffer ring, prefetch dist 2, counted vmcnt, one barrier per K-step)
template <int BN, bool OUT_F32>
__global__ __launch_bounds__(512, 1) void gemm256(const unsigned short* __restrict__ A,
                                                  const unsigned short* __restrict__ Bt,
                                                  void* __restrict__ Cp,
                                                  int M, int N, int K) {
  constexpr int NJ = BN / 64;
  constexpr int TC = 16 + BN / 16;
  constexpr int SPW = (TC + 7) / 8;
  constexpr int DUP = 8 * SPW - TC;

  __shared__ unsigned short AbL[3][8192];
  __shared__ unsigned short BbL[3][BN * 32];

  const int t512 = threadIdx.x;
  const int l = t512 & 63;
  const int wid = t512 >> 6;
  const int wm = wid >> 2, wn = wid & 3;
  const int lr = l & 15, lg = l >> 4;

  const int bid = blockIdx.y * 16 + blockIdx.x;
  const int nid = (bid & 7) * 32 + (bid >> 3);
  const int m0 = (nid >> 4) * 256, n0 = (nid & 15) * BN;

  const int lrow = l >> 2;
  const int scb = ((l & 3) << 4) ^ ((lrow & 3) << 4);
  const int rswz = (lr & 3) << 4;

  f32x4 acc[8][NJ];
#pragma unroll
  for (int i = 0; i < 8; ++i)
#pragma unroll
    for (int j = 0; j < NJ; ++j) acc[i][j] = (f32x4){0.f, 0.f, 0.f, 0.f};

  auto stage = [&](int buf, int t) {
    const int kt = t * 32;
#pragma unroll
    for (int s = 0; s < SPW; ++s) {
      int id = wid * SPW + s;
      if (DUP > 0 && id >= TC) id -= DUP;
      if (id < 16) {
        const char* src = (const char*)(A + (size_t)(m0 + id * 16 + lrow) * K + kt) + scb;
        __builtin_amdgcn_global_load_lds(
            (const __attribute__((address_space(1))) void*)src,
            (__attribute__((address_space(3))) void*)&AbL[buf][id * 512], 16, 0, 0);
      } else {
        const int b = id - 16;
        const char* src = (const char*)(Bt + (size_t)(n0 + b * 16 + lrow) * K + kt) + scb;
        __builtin_amdgcn_global_load_lds(
            (const __attribute__((address_space(1))) void*)src,
            (__attribute__((address_space(3))) void*)&BbL[buf][b * 512], 16, 0, 0);
      }
    }
  };

  const int NT = K / 32;

  stage(0, 0);
  stage(1, 1);
  if constexpr (SPW == 4) asm volatile("s_waitcnt vmcnt(4)" ::: "memory");
  else                    asm volatile("s_waitcnt vmcnt(3)" ::: "memory");
  __builtin_amdgcn_s_barrier();
  asm volatile("" ::: "memory");

  int cur = 0;
  for (int t = 0; t < NT; ++t) {
    int pf = cur + 2; if (pf >= 3) pf -= 3;
    if (t + 2 < NT) stage(pf, t + 2);

    const char* Ab0 = (const char*)&AbL[cur][0] + (size_t)(wm * 128 + lr) * 64;
    const char* Bb0 = (const char*)&BbL[cur][0] + (size_t)(wn * (BN / 4) + lr) * 64;
    bf16x8 af[8], bfv[NJ];
#pragma unroll
    for (int i = 0; i < 8; ++i)
      af[i] = *(const bf16x8*)(Ab0 + i * 1024 + ((lg * 16) ^ rswz));
#pragma unroll
    for (int j = 0; j < NJ; ++j)
      bfv[j] = *(const bf16x8*)(Bb0 + j * 1024 + ((lg * 16) ^ rswz));

    __builtin_amdgcn_s_setprio(1);
#pragma unroll
    for (int i = 0; i < 8; ++i)
#pragma unroll
      for (int j = 0; j < NJ; ++j)
        acc[i][j] = __builtin_amdgcn_mfma_f32_16x16x32_bf16(af[i], bfv[j], acc[i][j], 0, 0, 0);
    __builtin_amdgcn_s_setprio(0);

    if (t + 2 < NT) {
      if constexpr (SPW == 4) asm volatile("s_waitcnt vmcnt(4)" ::: "memory");
      else                    asm volatile("s_waitcnt vmcnt(3)" ::: "memory");
    } else if (t + 1 < NT) {
      asm volatile("s_waitcnt vmcnt(0)" ::: "memory");
    }
    if (t + 1 < NT) {
      asm volatile("s_waitcnt lgkmcnt(0)" ::: "memory");
      __builtin_amdgcn_s_barrier();
      asm volatile("" ::: "memory");
    }
    cur = (cur == 2) ? 0 : cur + 1;
  }

  const int row0 = m0 + wm * 128, col0 = n0 + wn * (BN / 4);
#pragma unroll
  for (int i = 0; i < 8; ++i) {
#pragma unroll
    for (int j = 0; j < NJ; ++j) {
      const int col = col0 + j * 16 + lr;
#pragma unroll
      for (int r = 0; r < 4; ++r) {
        const int row = row0 + i * 16 + lg * 4 + r;
        if (OUT_F32)
          ((float*)Cp)[(size_t)row * N + col] = acc[i][j][r];
        else
          ((unsigned short*)Cp)[(size_t)row * N + col] = f2bf(acc[i][j][r]);
      }
    }
  }
}

// ---------------- fused V-transpose(+kappa permute) AND RoPE ----------------
// blocks [0,512): Vt[kvh][d][tile*64+pos] = V[tile*64+pi(pos)][d]
// blocks [512, 512+20480): rope on Q/K with 0.125*log2e folded into Q
__global__ void vt_rope(const unsigned short* __restrict__ qkv_ro,
                        unsigned short* __restrict__ qkv,
                        unsigned short* __restrict__ Vt,
                        const float* __restrict__ fc,
                        const float* __restrict__ fs) {
  __shared__ unsigned short tile[64][72];
  const int b = blockIdx.x;
  const int t = threadIdx.x;
  if (b < 512) {
    const int kvh = b & 7;
    const int st = (b >> 3) * 64;
    const int sl = t >> 2, d0 = (t & 3) * 16;
    const unsigned short* src = qkv_ro + (size_t)(st + sl) * NQKV + 2560 + kvh * 64 + d0;
    *(bf16x8*)&tile[sl][d0] = *(const bf16x8*)src;
    *(bf16x8*)&tile[sl][d0 + 8] = *(const bf16x8*)(src + 8);
    __syncthreads();
    const int dl = t >> 2, s0 = (t & 3) * 16;
    unsigned short* dst = Vt + ((size_t)kvh * 64 + dl) * 4096 + st + s0;
#pragma unroll
    for (int j2 = 0; j2 < 2; ++j2) {
      short8 v;
#pragma unroll
      for (int j = 0; j < 8; ++j) {
        const int pos = s0 + j2 * 8 + j;
        const int key = (pos & 32) + ((pos & 4) << 2) + (((pos >> 3) & 3) << 2) + (pos & 3);
        v[j] = (short)tile[key][dl];
      }
      *(short8*)(dst + j2 * 8) = v;
    }
  } else {
    int idx = (b - 512) * 256 + t;
    int s = idx / 1280;
    int p = idx - s * 1280;
    bool isQ = (p < 1024);
    int col = isQ ? (p * 2) : (2048 + (p - 1024) * 2);
    int fi = (col >> 1) & 31;
    float c = fc[s * 32 + fi];
    float sn = fs[s * 32 + fi];
    unsigned short* ptr = qkv + (size_t)s * NQKV + col;
    float x0 = bf2f(ptr[0]);
    float x1 = bf2f(ptr[1]);
    float o0 = x0 * c - x1 * sn;
    float o1 = x0 * sn + x1 * c;
    float scl = isQ ? 0.1803368801111204f : 1.0f;  // 0.125 * log2(e) on Q only
    ptr[0] = f2bf(o0 * scl);
    ptr[1] = f2bf(o1 * scl);
  }
}

// ---------------- flash attention (round-12 verified, unchanged) ------------
__global__ __launch_bounds__(256, 4) void attn_fwd(const unsigned short* __restrict__ qkv,
                                                   const unsigned short* __restrict__ Vt,
                                                   unsigned short* __restrict__ attn) {
  __shared__ unsigned short Ks[2][4096];
  __shared__ unsigned short Vs[2][4096];

  const int t = threadIdx.x;
  const int l = t & 63;
  const int w = t >> 6;
  const int lr = l & 15, lg = l >> 4;
  const int h = blockIdx.x;
  const int kvh = h >> 2;
  const int qbase = blockIdx.y * 128 + w * 32;

  const int chunk0 = w * 2;
  const int srow = l >> 3;
  const int scol = (l & 7) * 16;
  const int sorig = scol ^ ((srow & 7) << 4);
  const char* ksrc0 = (const char*)(qkv + 2048 + kvh * 64) +
                      (size_t)(chunk0 * 8 + srow) * (NQKV * 2) + sorig;
  const char* ksrc1 = ksrc0 + 8 * (NQKV * 2);
  const char* vsrc0 = (const char*)(Vt + (size_t)kvh * 64 * 4096) +
                      (size_t)(chunk0 * 8 + srow) * 8192 + sorig;
  const char* vsrc1 = vsrc0 + 8 * 8192;

  const int x = (lr & 7) << 4;
  const int x6 = x & 64, x45 = x & 48;
  const int offA = lr * 128 + x6 + ((lg * 16) ^ x45);
  const int offB = lr * 128 + (64 ^ x6) + ((lg * 16) ^ x45);

  bf16x8 qf[2][2];
#pragma unroll
  for (int qi = 0; qi < 2; ++qi) {
    const unsigned short* qr = qkv + (size_t)(qbase + qi * 16 + lr) * NQKV + h * 64;
    qf[qi][0] = *(const bf16x8*)(qr + lg * 8);
    qf[qi][1] = *(const bf16x8*)(qr + 32 + lg * 8);
  }

  f32x4 ls4[2];
  f32x4 o[2][4];
#pragma unroll
  for (int qi = 0; qi < 2; ++qi) {
    ls4[qi] = (f32x4){0.f, 0.f, 0.f, 0.f};
#pragma unroll
    for (int c4 = 0; c4 < 4; ++c4) o[qi][c4] = (f32x4){0.f, 0.f, 0.f, 0.f};
  }

  auto stage = [&](int buf, int tile) {
    const size_t kadv = (size_t)tile * 64 * (NQKV * 2);
    const size_t vadv = (size_t)tile * 128;
    __builtin_amdgcn_global_load_lds(
        (const __attribute__((address_space(1))) void*)(ksrc0 + kadv),
        (__attribute__((address_space(3))) void*)&Ks[buf][chunk0 * 512], 16, 0, 0);
    __builtin_amdgcn_global_load_lds(
        (const __attribute__((address_space(1))) void*)(ksrc1 + kadv),
        (__attribute__((address_space(3))) void*)&Ks[buf][(chunk0 + 1) * 512], 16, 0, 0);
    __builtin_amdgcn_global_load_lds(
        (const __attribute__((address_space(1))) void*)(vsrc0 + vadv),
        (__attribute__((address_space(3))) void*)&Vs[buf][chunk0 * 512], 16, 0, 0);
    __builtin_amdgcn_global_load_lds(
        (const __attribute__((address_space(1))) void*)(vsrc1 + vadv),
        (__attribute__((address_space(3))) void*)&Vs[buf][(chunk0 + 1) * 512], 16, 0, 0);
  };

  stage(0, 0);
  asm volatile("s_waitcnt vmcnt(0)" ::: "memory");
  __syncthreads();

  const int NT = SEQ / 64;
  for (int tt = 0; tt < NT; ++tt) {
    const int buf = tt & 1;
    if (tt + 1 < NT) stage(buf ^ 1, tt + 1);

    const char* Ksb = (const char*)Ks[buf];
    const char* Vsb = (const char*)Vs[buf];

    f32x4 sc[2][4];
    __builtin_amdgcn_s_setprio(1);
#pragma unroll
    for (int sI = 0; sI < 4; ++sI) {
      bf16x8 kf0 = *(const bf16x8*)(Ksb + offA + sI * 2048);
      bf16x8 kf1 = *(const bf16x8*)(Ksb + offB + sI * 2048);
#pragma unroll
      for (int qi = 0; qi < 2; ++qi) {
        f32x4 c = (f32x4){0.f, 0.f, 0.f, 0.f};
        c = __builtin_amdgcn_mfma_f32_16x16x32_bf16(kf0, qf[qi][0], c, 0, 0, 0);
        c = __builtin_amdgcn_mfma_f32_16x16x32_bf16(kf1, qf[qi][1], c, 0, 0, 0);
        sc[qi][sI] = c;
      }
    }
    __builtin_amdgcn_s_setprio(0);

    bf16x8 pa[2][2];
#pragma unroll
    for (int qi = 0; qi < 2; ++qi) {
      float p[4][4];
#pragma unroll
      for (int sI = 0; sI < 4; ++sI)
#pragma unroll
        for (int r = 0; r < 4; ++r) p[sI][r] = exp2_fast(sc[qi][sI][r]);
#pragma unroll
      for (int sI = 0; sI < 4; ++sI)
#pragma unroll
        for (int r = 0; r < 4; ++r) ls4[qi][r] += p[sI][r];
      uint4v u1, u2;
      u1[0] = cvtpk_bf16(p[0][0], p[0][1]); u1[1] = cvtpk_bf16(p[0][2], p[0][3]);
      u1[2] = cvtpk_bf16(p[1][0], p[1][1]); u1[3] = cvtpk_bf16(p[1][2], p[1][3]);
      u2[0] = cvtpk_bf16(p[2][0], p[2][1]); u2[1] = cvtpk_bf16(p[2][2], p[2][3]);
      u2[2] = cvtpk_bf16(p[3][0], p[3][1]); u2[3] = cvtpk_bf16(p[3][2], p[3][3]);
      pa[qi][0] = __builtin_bit_cast(bf16x8, u1);
      pa[qi][1] = __builtin_bit_cast(bf16x8, u2);
    }

    __builtin_amdgcn_s_setprio(1);
#pragma unroll
    for (int c4 = 0; c4 < 4; ++c4) {
      bf16x8 v0 = *(const bf16x8*)(Vsb + offA + c4 * 2048);
      bf16x8 v1 = *(const bf16x8*)(Vsb + offB + c4 * 2048);
#pragma unroll
      for (int qi = 0; qi < 2; ++qi) {
        o[qi][c4] = __builtin_amdgcn_mfma_f32_16x16x32_bf16(pa[qi][0], v0, o[qi][c4], 0, 0, 0);
        o[qi][c4] = __builtin_amdgcn_mfma_f32_16x16x32_bf16(pa[qi][1], v1, o[qi][c4], 0, 0, 0);
      }
    }
    __builtin_amdgcn_s_setprio(0);

    if (tt + 1 < NT) {
      asm volatile("s_waitcnt vmcnt(0)" ::: "memory");
      __syncthreads();
    }
  }

#pragma unroll
  for (int qi = 0; qi < 2; ++qi) {
    float lsum = ls4[qi][0] + ls4[qi][1] + ls4[qi][2] + ls4[qi][3];
    lsum += __shfl_xor(lsum, 16, 64);
    lsum += __shfl_xor(lsum, 32, 64);
    float inv = 1.f / lsum;
    float invO[4];
#pragma unroll
    for (int r = 0; r < 4; ++r) invO[r] = __shfl(inv, 4 * lg + r, 64);
#pragma unroll
    for (int c4 = 0; c4 < 4; ++c4)
#pragma unroll
      for (int r = 0; r < 4; ++r) {
        attn[(size_t)(qbase + qi * 16 + 4 * lg + r) * 2048 + h * 64 + c4 * 16 + lr] =
            f2bf(o[qi][c4][r] * invO[r]);
      }
  }
}

// ---------------- launch ----------------
extern "C" void kernel_launch(void* const* d_in, const int* in_sizes, int n_in,
                              void* d_out, int out_size, void* d_ws, size_t ws_size,
                              hipStream_t stream) {
  const float* hs = (const float*)d_in[0];
  const float* wq = (const float*)d_in[1];
  const float* wk = (const float*)d_in[2];
  const float* wv = (const float*)d_in[3];
  const float* wo = (const float*)d_in[4];
  const float* fc = (const float*)d_in[5];
  const float* fs = (const float*)d_in[6];
  float* out = (float*)d_out;

  char* ws = (char*)d_ws;
  unsigned short* Xb    = (unsigned short*)(ws);                      // 0..32MB (X bf16)
  unsigned short* Wqkv  = (unsigned short*)(ws + (size_t)(32 << 20)); // 32..56MB
  unsigned short* Wob   = (unsigned short*)(ws + (size_t)(56 << 20)); // 56..64MB
  unsigned short* QKV   = (unsigned short*)(ws + (size_t)(64 << 20)); // 64..88MB
  unsigned short* attnb = Xb;                                         // 0..16MB (X dead)
  unsigned short* Vtb   = (unsigned short*)(ws + (size_t)(16 << 20)); // 16..20MB (X dead)

  cvt_all<<<32768, 256, 0, stream>>>(hs, wq, wk, wv, wo, Xb, Wqkv, Wob);

  // QKV = Xb @ Wqkv^T : M=4096, N=3072, K=4096 (bf16 out), 256x192 tiles
  gemm256<192, false><<<dim3(16, 16), 512, 0, stream>>>(Xb, Wqkv, QKV, 4096, 3072, 4096);

  // fused V-transpose(kappa) + RoPE (vt reads V-slice; rope writes Q/K only)
  vt_rope<<<20992, 256, 0, stream>>>(QKV, QKV, Vtb, fc, fs);

  attn_fwd<<<dim3(32, 32), 256, 0, stream>>>(QKV, Vtb, attnb);

  // out = attn @ Wo^T : M=4096, N=2048, K=2048 (fp32 out), 256x128 tiles
  gemm256<128, true><<<dim3(16, 16), 512, 0, stream>>>(attnb, Wob, out, 4096, 2048, 2048);
}

// Round 15
// 335.100 us; speedup vs baseline: 1.0428x; 1.0150x over previous
//
#include <hip/hip_runtime.h>
#include <hip/hip_bf16.h>

typedef __attribute__((ext_vector_type(4))) float f32x4;
typedef __attribute__((ext_vector_type(8))) __bf16 bf16x8;
typedef __attribute__((ext_vector_type(8))) short short8;
typedef __attribute__((ext_vector_type(4))) short short4v;
typedef __attribute__((ext_vector_type(2))) unsigned int uint2v;
typedef __attribute__((ext_vector_type(4))) unsigned int uint4v;

#define SEQ 4096
#define NQKV 3072

static __device__ __forceinline__ unsigned short f2bf(float x) {
  unsigned int u = __float_as_uint(x);
  u += 0x7fffu + ((u >> 16) & 1u);   // RTNE
  return (unsigned short)(u >> 16);
}
static __device__ __forceinline__ float bf2f(unsigned short b) {
  return __uint_as_float(((unsigned int)b) << 16);
}
static __device__ __forceinline__ unsigned int cvtpk_bf16(float lo, float hi) {
  unsigned int r;
  asm("v_cvt_pk_bf16_f32 %0, %1, %2" : "=v"(r) : "v"(lo), "v"(hi));
  return r;
}
static __device__ __forceinline__ float exp2_fast(float x) {
  float r;
  asm("v_exp_f32 %0, %1" : "=v"(r) : "v"(x));
  return r;
}

// ---------------- fused fp32 -> bf16 convert (single launch) ----------------
__global__ void cvt_all(const float* __restrict__ hs, const float* __restrict__ wq,
                        const float* __restrict__ wk, const float* __restrict__ wv,
                        const float* __restrict__ wo,
                        unsigned short* __restrict__ Xb, unsigned short* __restrict__ Wqkv,
                        unsigned short* __restrict__ Wob) {
  int i = blockIdx.x * blockDim.x + threadIdx.x;   // 8388608 total
  const float* src;
  unsigned short* dst;
  int off;
  if (i < 4194304)      { src = hs; dst = Xb;              off = i; }
  else if (i < 6291456) { src = wq; dst = Wqkv;            off = i - 4194304; }
  else if (i < 6815744) { src = wk; dst = Wqkv + 8388608;  off = i - 6291456; }
  else if (i < 7340032) { src = wv; dst = Wqkv + 10485760; off = i - 6815744; }
  else                  { src = wo; dst = Wob;             off = i - 7340032; }
  f32x4 v = ((const f32x4*)src)[off];
  short4v o;
#pragma unroll
  for (int j = 0; j < 4; ++j) o[j] = (short)f2bf(v[j]);
  ((short4v*)dst)[off] = o;
}

// ---------------- deep-pipelined bf16 GEMM: C = A(MxK) @ Bt(NxK)^T ----------
// round-12 structure (3-buffer ring, dist-2 counted vmcnt, one barrier/K-step)
// NEW: wave split 4M x 2N (was 2M x 4N) -> per-wave frags (4 A + BN/32 B)
// instead of (8 A + BN/64 B): LDS read traffic -9% (BN=192) / -20% (BN=128),
// attacking the LDS-pipe oversubscription (352 vs 232 matrix clk per step).
template <int BN, bool OUT_F32>
__global__ __launch_bounds__(512, 1) void gemm256(const unsigned short* __restrict__ A,
                                                  const unsigned short* __restrict__ Bt,
                                                  void* __restrict__ Cp,
                                                  int M, int N, int K) {
  constexpr int NJ = BN / 32;            // B-frags per wave (2 N-waves)
  constexpr int TC = 16 + BN / 16;
  constexpr int SPW = (TC + 7) / 8;
  constexpr int DUP = 8 * SPW - TC;

  __shared__ unsigned short AbL[3][8192];
  __shared__ unsigned short BbL[3][BN * 32];

  const int t512 = threadIdx.x;
  const int l = t512 & 63;
  const int wid = t512 >> 6;
  const int wm = wid & 3, wn = wid >> 2;   // 4 M-waves x 2 N-waves
  const int lr = l & 15, lg = l >> 4;

  const int bid = blockIdx.y * 16 + blockIdx.x;
  const int nid = (bid & 7) * 32 + (bid >> 3);
  const int m0 = (nid >> 4) * 256, n0 = (nid & 15) * BN;

  const int lrow = l >> 2;
  const int scb = ((l & 3) << 4) ^ ((lrow & 3) << 4);
  const int rswz = (lr & 3) << 4;

  f32x4 acc[4][NJ];
#pragma unroll
  for (int i = 0; i < 4; ++i)
#pragma unroll
    for (int j = 0; j < NJ; ++j) acc[i][j] = (f32x4){0.f, 0.f, 0.f, 0.f};

  auto stage = [&](int buf, int t) {
    const int kt = t * 32;
#pragma unroll
    for (int s = 0; s < SPW; ++s) {
      int id = wid * SPW + s;
      if (DUP > 0 && id >= TC) id -= DUP;
      if (id < 16) {
        const char* src = (const char*)(A + (size_t)(m0 + id * 16 + lrow) * K + kt) + scb;
        __builtin_amdgcn_global_load_lds(
            (const __attribute__((address_space(1))) void*)src,
            (__attribute__((address_space(3))) void*)&AbL[buf][id * 512], 16, 0, 0);
      } else {
        const int b = id - 16;
        const char* src = (const char*)(Bt + (size_t)(n0 + b * 16 + lrow) * K + kt) + scb;
        __builtin_amdgcn_global_load_lds(
            (const __attribute__((address_space(1))) void*)src,
            (__attribute__((address_space(3))) void*)&BbL[buf][b * 512], 16, 0, 0);
      }
    }
  };

  const int NT = K / 32;

  stage(0, 0);
  stage(1, 1);
  if constexpr (SPW == 4) asm volatile("s_waitcnt vmcnt(4)" ::: "memory");
  else                    asm volatile("s_waitcnt vmcnt(3)" ::: "memory");
  __builtin_amdgcn_s_barrier();
  asm volatile("" ::: "memory");

  int cur = 0;
  for (int t = 0; t < NT; ++t) {
    int pf = cur + 2; if (pf >= 3) pf -= 3;
    if (t + 2 < NT) stage(pf, t + 2);

    const char* Ab0 = (const char*)&AbL[cur][0] + (size_t)(wm * 64 + lr) * 64;
    const char* Bb0 = (const char*)&BbL[cur][0] + (size_t)(wn * (BN / 2) + lr) * 64;
    bf16x8 af[4], bfv[NJ];
#pragma unroll
    for (int i = 0; i < 4; ++i)
      af[i] = *(const bf16x8*)(Ab0 + i * 1024 + ((lg * 16) ^ rswz));
#pragma unroll
    for (int j = 0; j < NJ; ++j)
      bfv[j] = *(const bf16x8*)(Bb0 + j * 1024 + ((lg * 16) ^ rswz));

    __builtin_amdgcn_s_setprio(1);
#pragma unroll
    for (int i = 0; i < 4; ++i)
#pragma unroll
      for (int j = 0; j < NJ; ++j)
        acc[i][j] = __builtin_amdgcn_mfma_f32_16x16x32_bf16(af[i], bfv[j], acc[i][j], 0, 0, 0);
    __builtin_amdgcn_s_setprio(0);

    if (t + 2 < NT) {
      if constexpr (SPW == 4) asm volatile("s_waitcnt vmcnt(4)" ::: "memory");
      else                    asm volatile("s_waitcnt vmcnt(3)" ::: "memory");
    } else if (t + 1 < NT) {
      asm volatile("s_waitcnt vmcnt(0)" ::: "memory");
    }
    if (t + 1 < NT) {
      asm volatile("s_waitcnt lgkmcnt(0)" ::: "memory");
      __builtin_amdgcn_s_barrier();
      asm volatile("" ::: "memory");
    }
    cur = (cur == 2) ? 0 : cur + 1;
  }

  const int row0 = m0 + wm * 64, col0 = n0 + wn * (BN / 2);
#pragma unroll
  for (int i = 0; i < 4; ++i) {
#pragma unroll
    for (int j = 0; j < NJ; ++j) {
      const int col = col0 + j * 16 + lr;
#pragma unroll
      for (int r = 0; r < 4; ++r) {
        const int row = row0 + i * 16 + lg * 4 + r;
        if (OUT_F32)
          ((float*)Cp)[(size_t)row * N + col] = acc[i][j][r];
        else
          ((unsigned short*)Cp)[(size_t)row * N + col] = f2bf(acc[i][j][r]);
      }
    }
  }
}

// ---------------- fused V-transpose(+kappa permute) AND RoPE ----------------
__global__ void vt_rope(const unsigned short* __restrict__ qkv_ro,
                        unsigned short* __restrict__ qkv,
                        unsigned short* __restrict__ Vt,
                        const float* __restrict__ fc,
                        const float* __restrict__ fs) {
  __shared__ unsigned short tile[64][72];
  const int b = blockIdx.x;
  const int t = threadIdx.x;
  if (b < 512) {
    const int kvh = b & 7;
    const int st = (b >> 3) * 64;
    const int sl = t >> 2, d0 = (t & 3) * 16;
    const unsigned short* src = qkv_ro + (size_t)(st + sl) * NQKV + 2560 + kvh * 64 + d0;
    *(bf16x8*)&tile[sl][d0] = *(const bf16x8*)src;
    *(bf16x8*)&tile[sl][d0 + 8] = *(const bf16x8*)(src + 8);
    __syncthreads();
    const int dl = t >> 2, s0 = (t & 3) * 16;
    unsigned short* dst = Vt + ((size_t)kvh * 64 + dl) * 4096 + st + s0;
#pragma unroll
    for (int j2 = 0; j2 < 2; ++j2) {
      short8 v;
#pragma unroll
      for (int j = 0; j < 8; ++j) {
        const int pos = s0 + j2 * 8 + j;
        const int key = (pos & 32) + ((pos & 4) << 2) + (((pos >> 3) & 3) << 2) + (pos & 3);
        v[j] = (short)tile[key][dl];
      }
      *(short8*)(dst + j2 * 8) = v;
    }
  } else {
    int idx = (b - 512) * 256 + t;
    int s = idx / 1280;
    int p = idx - s * 1280;
    bool isQ = (p < 1024);
    int col = isQ ? (p * 2) : (2048 + (p - 1024) * 2);
    int fi = (col >> 1) & 31;
    float c = fc[s * 32 + fi];
    float sn = fs[s * 32 + fi];
    unsigned short* ptr = qkv + (size_t)s * NQKV + col;
    float x0 = bf2f(ptr[0]);
    float x1 = bf2f(ptr[1]);
    float o0 = x0 * c - x1 * sn;
    float o1 = x0 * sn + x1 * c;
    float scl = isQ ? 0.1803368801111204f : 1.0f;  // 0.125 * log2(e) on Q only
    ptr[0] = f2bf(o0 * scl);
    ptr[1] = f2bf(o1 * scl);
  }
}

// ---------------- flash attention (round-12 verified, unchanged) ------------
__global__ __launch_bounds__(256, 4) void attn_fwd(const unsigned short* __restrict__ qkv,
                                                   const unsigned short* __restrict__ Vt,
                                                   unsigned short* __restrict__ attn) {
  __shared__ unsigned short Ks[2][4096];
  __shared__ unsigned short Vs[2][4096];

  const int t = threadIdx.x;
  const int l = t & 63;
  const int w = t >> 6;
  const int lr = l & 15, lg = l >> 4;
  const int h = blockIdx.x;
  const int kvh = h >> 2;
  const int qbase = blockIdx.y * 128 + w * 32;

  const int chunk0 = w * 2;
  const int srow = l >> 3;
  const int scol = (l & 7) * 16;
  const int sorig = scol ^ ((srow & 7) << 4);
  const char* ksrc0 = (const char*)(qkv + 2048 + kvh * 64) +
                      (size_t)(chunk0 * 8 + srow) * (NQKV * 2) + sorig;
  const char* ksrc1 = ksrc0 + 8 * (NQKV * 2);
  const char* vsrc0 = (const char*)(Vt + (size_t)kvh * 64 * 4096) +
                      (size_t)(chunk0 * 8 + srow) * 8192 + sorig;
  const char* vsrc1 = vsrc0 + 8 * 8192;

  const int x = (lr & 7) << 4;
  const int x6 = x & 64, x45 = x & 48;
  const int offA = lr * 128 + x6 + ((lg * 16) ^ x45);
  const int offB = lr * 128 + (64 ^ x6) + ((lg * 16) ^ x45);

  bf16x8 qf[2][2];
#pragma unroll
  for (int qi = 0; qi < 2; ++qi) {
    const unsigned short* qr = qkv + (size_t)(qbase + qi * 16 + lr) * NQKV + h * 64;
    qf[qi][0] = *(const bf16x8*)(qr + lg * 8);
    qf[qi][1] = *(const bf16x8*)(qr + 32 + lg * 8);
  }

  f32x4 ls4[2];
  f32x4 o[2][4];
#pragma unroll
  for (int qi = 0; qi < 2; ++qi) {
    ls4[qi] = (f32x4){0.f, 0.f, 0.f, 0.f};
#pragma unroll
    for (int c4 = 0; c4 < 4; ++c4) o[qi][c4] = (f32x4){0.f, 0.f, 0.f, 0.f};
  }

  auto stage = [&](int buf, int tile) {
    const size_t kadv = (size_t)tile * 64 * (NQKV * 2);
    const size_t vadv = (size_t)tile * 128;
    __builtin_amdgcn_global_load_lds(
        (const __attribute__((address_space(1))) void*)(ksrc0 + kadv),
        (__attribute__((address_space(3))) void*)&Ks[buf][chunk0 * 512], 16, 0, 0);
    __builtin_amdgcn_global_load_lds(
        (const __attribute__((address_space(1))) void*)(ksrc1 + kadv),
        (__attribute__((address_space(3))) void*)&Ks[buf][(chunk0 + 1) * 512], 16, 0, 0);
    __builtin_amdgcn_global_load_lds(
        (const __attribute__((address_space(1))) void*)(vsrc0 + vadv),
        (__attribute__((address_space(3))) void*)&Vs[buf][chunk0 * 512], 16, 0, 0);
    __builtin_amdgcn_global_load_lds(
        (const __attribute__((address_space(1))) void*)(vsrc1 + vadv),
        (__attribute__((address_space(3))) void*)&Vs[buf][(chunk0 + 1) * 512], 16, 0, 0);
  };

  stage(0, 0);
  asm volatile("s_waitcnt vmcnt(0)" ::: "memory");
  __syncthreads();

  const int NT = SEQ / 64;
  for (int tt = 0; tt < NT; ++tt) {
    const int buf = tt & 1;
    if (tt + 1 < NT) stage(buf ^ 1, tt + 1);

    const char* Ksb = (const char*)Ks[buf];
    const char* Vsb = (const char*)Vs[buf];

    f32x4 sc[2][4];
    __builtin_amdgcn_s_setprio(1);
#pragma unroll
    for (int sI = 0; sI < 4; ++sI) {
      bf16x8 kf0 = *(const bf16x8*)(Ksb + offA + sI * 2048);
      bf16x8 kf1 = *(const bf16x8*)(Ksb + offB + sI * 2048);
#pragma unroll
      for (int qi = 0; qi < 2; ++qi) {
        f32x4 c = (f32x4){0.f, 0.f, 0.f, 0.f};
        c = __builtin_amdgcn_mfma_f32_16x16x32_bf16(kf0, qf[qi][0], c, 0, 0, 0);
        c = __builtin_amdgcn_mfma_f32_16x16x32_bf16(kf1, qf[qi][1], c, 0, 0, 0);
        sc[qi][sI] = c;
      }
    }
    __builtin_amdgcn_s_setprio(0);

    bf16x8 pa[2][2];
#pragma unroll
    for (int qi = 0; qi < 2; ++qi) {
      float p[4][4];
#pragma unroll
      for (int sI = 0; sI < 4; ++sI)
#pragma unroll
        for (int r = 0; r < 4; ++r) p[sI][r] = exp2_fast(sc[qi][sI][r]);
#pragma unroll
      for (int sI = 0; sI < 4; ++sI)
#pragma unroll
        for (int r = 0; r < 4; ++r) ls4[qi][r] += p[sI][r];
      uint4v u1, u2;
      u1[0] = cvtpk_bf16(p[0][0], p[0][1]); u1[1] = cvtpk_bf16(p[0][2], p[0][3]);
      u1[2] = cvtpk_bf16(p[1][0], p[1][1]); u1[3] = cvtpk_bf16(p[1][2], p[1][3]);
      u2[0] = cvtpk_bf16(p[2][0], p[2][1]); u2[1] = cvtpk_bf16(p[2][2], p[2][3]);
      u2[2] = cvtpk_bf16(p[3][0], p[3][1]); u2[3] = cvtpk_bf16(p[3][2], p[3][3]);
      pa[qi][0] = __builtin_bit_cast(bf16x8, u1);
      pa[qi][1] = __builtin_bit_cast(bf16x8, u2);
    }

    __builtin_amdgcn_s_setprio(1);
#pragma unroll
    for (int c4 = 0; c4 < 4; ++c4) {
      bf16x8 v0 = *(const bf16x8*)(Vsb + offA + c4 * 2048);
      bf16x8 v1 = *(const bf16x8*)(Vsb + offB + c4 * 2048);
#pragma unroll
      for (int qi = 0; qi < 2; ++qi) {
        o[qi][c4] = __builtin_amdgcn_mfma_f32_16x16x32_bf16(pa[qi][0], v0, o[qi][c4], 0, 0, 0);
        o[qi][c4] = __builtin_amdgcn_mfma_f32_16x16x32_bf16(pa[qi][1], v1, o[qi][c4], 0, 0, 0);
      }
    }
    __builtin_amdgcn_s_setprio(0);

    if (tt + 1 < NT) {
      asm volatile("s_waitcnt vmcnt(0)" ::: "memory");
      __syncthreads();
    }
  }

#pragma unroll
  for (int qi = 0; qi < 2; ++qi) {
    float lsum = ls4[qi][0] + ls4[qi][1] + ls4[qi][2] + ls4[qi][3];
    lsum += __shfl_xor(lsum, 16, 64);
    lsum += __shfl_xor(lsum, 32, 64);
    float inv = 1.f / lsum;
    float invO[4];
#pragma unroll
    for (int r = 0; r < 4; ++r) invO[r] = __shfl(inv, 4 * lg + r, 64);
#pragma unroll
    for (int c4 = 0; c4 < 4; ++c4)
#pragma unroll
      for (int r = 0; r < 4; ++r) {
        attn[(size_t)(qbase + qi * 16 + 4 * lg + r) * 2048 + h * 64 + c4 * 16 + lr] =
            f2bf(o[qi][c4][r] * invO[r]);
      }
  }
}

// ---------------- launch ----------------
extern "C" void kernel_launch(void* const* d_in, const int* in_sizes, int n_in,
                              void* d_out, int out_size, void* d_ws, size_t ws_size,
                              hipStream_t stream) {
  const float* hs = (const float*)d_in[0];
  const float* wq = (const float*)d_in[1];
  const float* wk = (const float*)d_in[2];
  const float* wv = (const float*)d_in[3];
  const float* wo = (const float*)d_in[4];
  const float* fc = (const float*)d_in[5];
  const float* fs = (const float*)d_in[6];
  float* out = (float*)d_out;

  char* ws = (char*)d_ws;
  unsigned short* Xb    = (unsigned short*)(ws);                      // 0..32MB (X bf16)
  unsigned short* Wqkv  = (unsigned short*)(ws + (size_t)(32 << 20)); // 32..56MB
  unsigned short* Wob   = (unsigned short*)(ws + (size_t)(56 << 20)); // 56..64MB
  unsigned short* QKV   = (unsigned short*)(ws + (size_t)(64 << 20)); // 64..88MB
  unsigned short* attnb = Xb;                                         // 0..16MB (X dead)
  unsigned short* Vtb   = (unsigned short*)(ws + (size_t)(16 << 20)); // 16..20MB (X dead)

  cvt_all<<<32768, 256, 0, stream>>>(hs, wq, wk, wv, wo, Xb, Wqkv, Wob);

  // QKV = Xb @ Wqkv^T : M=4096, N=3072, K=4096 (bf16 out), 256x192 tiles
  gemm256<192, false><<<dim3(16, 16), 512, 0, stream>>>(Xb, Wqkv, QKV, 4096, 3072, 4096);

  // fused V-transpose(kappa) + RoPE
  vt_rope<<<20992, 256, 0, stream>>>(QKV, QKV, Vtb, fc, fs);

  attn_fwd<<<dim3(32, 32), 256, 0, stream>>>(QKV, Vtb, attnb);

  // out = attn @ Wo^T : M=4096, N=2048, K=2048 (fp32 out), 256x128 tiles
  gemm256<128, true><<<dim3(16, 16), 512, 0, stream>>>(attnb, Wob, out, 4096, 2048, 2048);
}